// Round 5
// baseline (777.770 us; speedup 1.0000x reference)
//
#include <hip/hip_runtime.h>
#include <hip/hip_bf16.h>
#include <cstdint>

#define B_  64
#define T_  32
#define E_  300
#define EP  320      // padded K for the x-precompute GEMM
#define H_  1024
#define G4  4096     // 4*H
#define BH  65536    // B_*H_
#define NBLK 192     // persistent blocks: 64 L1 + 128 L2
#define NSS  33      // supersteps (2-stage pipeline over 32 timesteps)

typedef __attribute__((ext_vector_type(8))) short bf16x8;
typedef __attribute__((ext_vector_type(4))) float f32x4;
typedef unsigned short ushort_t;

__device__ __forceinline__ bf16x8 load_b8(const ushort_t* p) {
    union { uint4 u; bf16x8 v; } c;
    c.u = *reinterpret_cast<const uint4*>(p);
    return c.v;
}

__device__ __forceinline__ ushort_t f2bf(float x) {
    union { float f; uint32_t u; } c; c.f = x;
    uint32_t r = c.u + 0x7fffu + ((c.u >> 16) & 1u);   // RNE
    return (ushort_t)(r >> 16);
}

__device__ __forceinline__ float sigm(float x) { return 1.0f / (1.0f + __expf(-x)); }

// agent-scope write-through store (producer side); consumers use plain cached
// loads — each timestep gets a unique buffer slot, so no stale lines exist.
__device__ __forceinline__ void astore16(ushort_t* p, ushort_t v) {
    __hip_atomic_store(p, v, __ATOMIC_RELAXED, __HIP_MEMORY_SCOPE_AGENT);
}

// ---------------- prep kernels ----------------

__global__ void pad_convert_wih1(const float* __restrict__ src, ushort_t* __restrict__ dst) {
    int i = blockIdx.x * blockDim.x + threadIdx.x;
    int stride = gridDim.x * blockDim.x;
    const int n = G4 * EP;
    for (; i < n; i += stride) {
        int r = i / EP, c = i - r * EP;
        dst[i] = (c < E_) ? f2bf(src[r * E_ + c]) : (ushort_t)0;
    }
}

__global__ void gather_embed(const int* __restrict__ q, const float* __restrict__ table,
                             ushort_t* __restrict__ Xp) {
    int i = blockIdx.x * blockDim.x + threadIdx.x;
    int stride = gridDim.x * blockDim.x;
    const int n = B_ * T_ * EP;
    for (; i < n; i += stride) {
        int r = i / EP, c = i - r * EP;
        Xp[i] = (c < E_) ? f2bf(table[q[r] * E_ + c]) : (ushort_t)0;
    }
}

// ---------------- x-part precompute GEMM ----------------
// xg[t][b][4H] = Xp @ Wih1p^T + (b_ih1+b_hh1)
__launch_bounds__(256)
__global__ void xgemm(const ushort_t* __restrict__ Xp, const ushort_t* __restrict__ Wp,
                      const float* __restrict__ b_ih1, const float* __restrict__ b_hh1,
                      float* __restrict__ xg) {
    int mblk = blockIdx.x, nblk = blockIdx.y;
    int wave = threadIdx.x >> 6, lane = threadIdx.x & 63;
    int lm = lane & 15, lq = lane >> 4;
    int m0 = mblk * 64 + wave * 16;
    f32x4 acc[4];
    #pragma unroll
    for (int g = 0; g < 4; ++g) {
        int n = nblk * 64 + g * 16 + lm;
        float bv = b_ih1[n] + b_hh1[n];
        acc[g] = (f32x4){bv, bv, bv, bv};
    }
    for (int k0 = 0; k0 < EP; k0 += 32) {
        bf16x8 a = load_b8(Xp + (m0 + lm) * EP + k0 + lq * 8);
        #pragma unroll
        for (int g = 0; g < 4; ++g) {
            bf16x8 b = load_b8(Wp + (nblk * 64 + g * 16 + lm) * EP + k0 + lq * 8);
            acc[g] = __builtin_amdgcn_mfma_f32_16x16x32_bf16(a, b, acc[g], 0, 0, 0);
        }
    }
    #pragma unroll
    for (int g = 0; g < 4; ++g)
        #pragma unroll
        for (int r = 0; r < 4; ++r) {
            int m = m0 + lq * 4 + r;          // m = b*T + t
            int b = m >> 5, t = m & 31;
            int n = nblk * 64 + g * 16 + lm;
            xg[((size_t)t * B_ + b) * G4 + n] = acc[g][r];
        }
}

// ---------------- persistent recurrence kernel ----------------
// blocks 0-63:   L1, 16-col slices, Whh1 in LDS (fragment layout, 128 KB)
// blocks 64-191: L2, 8-col slices, Wih2 + Whh2 in LDS (2 x 64 KB)
// LDS fragment layout: chunk (k0c, tile) is 512 shorts; lane l's 16 B at l*8.

__global__ __launch_bounds__(256, 1) void lstm_persist(
    const float* __restrict__ Whh1, const float* __restrict__ Wih2,
    const float* __restrict__ Whh2,
    const float* __restrict__ b_ih2, const float* __restrict__ b_hh2,
    const float* __restrict__ xg, const int* __restrict__ qlen,
    ushort_t* __restrict__ h1hist,   // 33 slots of BH bf16; slot k = h1(k-1)
    ushort_t* __restrict__ h2hist,   // 33 slots of BH bf16; slot k = h2(k-1)
    float* __restrict__ h1f, float* __restrict__ c1f,
    float* __restrict__ h2f, float* __restrict__ c2f,
    int* __restrict__ ctr)
{
    __shared__ ushort_t ws[65536];      // 128 KB, fragment layout

    const int blk  = blockIdx.x;
    const int role = (blk >= 64);       // 0=L1, 1=L2
    const int tid  = threadIdx.x;
    const int wave = tid >> 6, lane = tid & 63;
    const int lm = lane & 15, lq = lane >> 4;
    const int m0 = wave * 16;

    // ---- stage weights fp32 -> bf16 fragment layout (once) ----
    // each thread covers one float4 (k = tid*4 .. +3) of every weight row
    {
        const int k0c = tid >> 3;               // k/32
        const int klq = (tid >> 1) & 3;         // (k>>3)&3
        const int ke  = (tid & 1) * 4;          // k&7 (0 or 4)
        if (!role) {
            const int js = blk;                 // 16-col slice
            for (int r = 0; r < 64; ++r) {      // r = g*16 + lmt
                int g = r >> 4, lmt = r & 15;
                const float4 v = reinterpret_cast<const float4*>(
                    Whh1 + (size_t)(g * H_ + js * 16 + lmt) * H_)[tid];
                uint2 pk;
                pk.x = (uint32_t)f2bf(v.x) | ((uint32_t)f2bf(v.y) << 16);
                pk.y = (uint32_t)f2bf(v.z) | ((uint32_t)f2bf(v.w) << 16);
                int off = ((k0c * 4 + g) * 64 + klq * 16 + lmt) * 8 + ke;  // shorts
                *reinterpret_cast<uint2*>(ws + off) = pk;
            }
        } else {
            const int jj0 = (blk - 64) * 8;     // 8-col slice
            for (int m = 0; m < 2; ++m) {
                const float* Wm = m ? Whh2 : Wih2;
                for (int r = 0; r < 32; ++r) {  // r = g*8 + jj
                    int g = r >> 3, jj = r & 7;
                    int tl = r >> 4, lmt = r & 15;
                    const float4 v = reinterpret_cast<const float4*>(
                        Wm + (size_t)(g * H_ + jj0 + jj) * H_)[tid];
                    uint2 pk;
                    pk.x = (uint32_t)f2bf(v.x) | ((uint32_t)f2bf(v.y) << 16);
                    pk.y = (uint32_t)f2bf(v.z) | ((uint32_t)f2bf(v.w) << 16);
                    int off = m * 32768 + ((k0c * 2 + tl) * 64 + klq * 16 + lmt) * 8 + ke;
                    *reinterpret_cast<uint2*>(ws + off) = pk;
                }
            }
        }
    }
    __syncthreads();

    int q[4];
    #pragma unroll
    for (int r = 0; r < 4; ++r) q[r] = qlen[m0 + lq * 4 + r];

    // L2 per-lane bias for its two tiles (gate depends on lm)
    float bi0 = 0.f, bi1 = 0.f;
    if (role) {
        const int jj0 = (blk - 64) * 8;
        int jj = lm & 7;
        int g0 = (lm < 8) ? 0 : 1, g1 = g0 + 2;
        bi0 = b_ih2[g0 * H_ + jj0 + jj] + b_hh2[g0 * H_ + jj0 + jj];
        bi1 = b_ih2[g1 * H_ + jj0 + jj] + b_hh2[g1 * H_ + jj0 + jj];
    }

    float    c_reg[4]  = {0.f, 0.f, 0.f, 0.f};
    float    h_reg[4]  = {0.f, 0.f, 0.f, 0.f};
    ushort_t hb_reg[4] = {0, 0, 0, 0};

    for (int s = 0; s < NSS; ++s) {
        if (!role && s < 32) {
            // ---- L1: h1(t) = cell(Whh1*h1(t-1) + xg[t]) ----
            const int t = s;
            const int js = blk;
            const ushort_t* hp = h1hist + (size_t)t * BH;
            ushort_t*       hn = h1hist + (size_t)(t + 1) * BH;
            f32x4 acc[4];
            #pragma unroll
            for (int g = 0; g < 4; ++g)
                #pragma unroll
                for (int r = 0; r < 4; ++r)
                    acc[g][r] = xg[((size_t)t * B_ + (m0 + lq * 4 + r)) * G4 + g * H_ + js * 16 + lm];

            const uint4* hr = reinterpret_cast<const uint4*>(hp + (size_t)(m0 + lm) * H_);
            uint4 buf0[8], buf1[8];
            #pragma unroll
            for (int i = 0; i < 8; ++i) buf0[i] = hr[i * 4 + lq];
            #pragma unroll
            for (int grp = 0; grp < 4; ++grp) {
                const uint4* cur = (grp & 1) ? buf1 : buf0;
                uint4*       nxt = (grp & 1) ? buf0 : buf1;
                if (grp < 3) {
                    #pragma unroll
                    for (int i = 0; i < 8; ++i) nxt[i] = hr[(grp + 1) * 32 + i * 4 + lq];
                }
                #pragma unroll
                for (int i = 0; i < 8; ++i) {
                    int k0c = grp * 8 + i;
                    union { uint4 u; bf16x8 v; } a; a.u = cur[i];
                    #pragma unroll
                    for (int g = 0; g < 4; ++g) {
                        bf16x8 bb = load_b8(ws + ((k0c * 4 + g) << 9) + lane * 8);
                        acc[g] = __builtin_amdgcn_mfma_f32_16x16x32_bf16(a.v, bb, acc[g], 0, 0, 0);
                    }
                }
            }
            #pragma unroll
            for (int r = 0; r < 4; ++r) {
                int b = m0 + lq * 4 + r, j = js * 16 + lm;
                if (t < q[r]) {
                    float iv = sigm(acc[0][r]);
                    float fv = sigm(acc[1][r]);
                    float gv = tanhf(acc[2][r]);
                    float ov = sigm(acc[3][r]);
                    float cn = fv * c_reg[r] + iv * gv;
                    float hv = ov * tanhf(cn);
                    c_reg[r] = cn; h_reg[r] = hv;
                    hb_reg[r] = f2bf(hv);
                }
                astore16(&hn[b * H_ + j], hb_reg[r]);
            }
        } else if (role && s >= 1) {
            // ---- L2: gates = Wih2*h1(t) + bias2 + Whh2*h2(t-1); h2(t) = cell ----
            const int t = s - 1;
            const int jj0 = (blk - 64) * 8;
            const ushort_t* h1p = h1hist + (size_t)s * BH;        // h1(t)
            const ushort_t* h2p = h2hist + (size_t)t * BH;        // h2(t-1)
            ushort_t*       h2n = h2hist + (size_t)(t + 1) * BH;  // h2(t)
            f32x4 acc[2];
            acc[0] = (f32x4){bi0, bi0, bi0, bi0};
            acc[1] = (f32x4){bi1, bi1, bi1, bi1};

            #pragma unroll
            for (int mat = 0; mat < 2; ++mat) {
                const ushort_t* hv = mat ? h2p : h1p;
                const uint4* hr = reinterpret_cast<const uint4*>(hv + (size_t)(m0 + lm) * H_);
                uint4 buf0[8], buf1[8];
                #pragma unroll
                for (int i = 0; i < 8; ++i) buf0[i] = hr[i * 4 + lq];
                #pragma unroll
                for (int grp = 0; grp < 4; ++grp) {
                    const uint4* cur = (grp & 1) ? buf1 : buf0;
                    uint4*       nxt = (grp & 1) ? buf0 : buf1;
                    if (grp < 3) {
                        #pragma unroll
                        for (int i = 0; i < 8; ++i) nxt[i] = hr[(grp + 1) * 32 + i * 4 + lq];
                    }
                    #pragma unroll
                    for (int i = 0; i < 8; ++i) {
                        int k0c = grp * 8 + i;
                        union { uint4 u; bf16x8 v; } a; a.u = cur[i];
                        #pragma unroll
                        for (int tl = 0; tl < 2; ++tl) {
                            bf16x8 bb = load_b8(ws + mat * 32768 + ((k0c * 2 + tl) << 9) + lane * 8);
                            acc[tl] = __builtin_amdgcn_mfma_f32_16x16x32_bf16(a.v, bb, acc[tl], 0, 0, 0);
                        }
                    }
                }
            }
            // epilogue: tile0 lanes lm<8 hold gate i, lm>=8 gate f;
            //           tile1 lanes lm<8 hold gate g, lm>=8 gate o.
            #pragma unroll
            for (int r = 0; r < 4; ++r) {
                float a0 = sigm(acc[0][r]);                            // i or f
                float a1 = (lm < 8) ? tanhf(acc[1][r]) : sigm(acc[1][r]); // g or o
                float fo0 = __shfl_xor(a0, 8);                         // f for lm<8
                float fo1 = __shfl_xor(a1, 8);                         // o for lm<8
                if (lm < 8) {
                    int b = m0 + lq * 4 + r, j = jj0 + lm;
                    if (t < q[r]) {
                        float cn = fo0 * c_reg[r] + a0 * a1;
                        float hv = fo1 * tanhf(cn);
                        c_reg[r] = cn; h_reg[r] = hv;
                        hb_reg[r] = f2bf(hv);
                    }
                    astore16(&h2n[b * H_ + j], hb_reg[r]);
                }
            }
        }

        if (s < NSS - 1) {
            __syncthreads();   // drains vmcnt(0): all sc1 stores visible
            if (tid == 0) {
                __hip_atomic_fetch_add(&ctr[(s * 16 + (blk & 15)) * 32], 1,
                                       __ATOMIC_RELAXED, __HIP_MEMORY_SCOPE_AGENT);
                int sum;
                do {
                    sum = 0;
                    #pragma unroll
                    for (int k = 0; k < 16; ++k)
                        sum += __hip_atomic_load(&ctr[(s * 16 + k) * 32],
                                                 __ATOMIC_RELAXED, __HIP_MEMORY_SCOPE_AGENT);
                    if (sum < NBLK) __builtin_amdgcn_s_sleep(1);
                } while (sum < NBLK);
            }
            __syncthreads();
        }
    }

    // final states (next dispatch sees them via inter-dispatch coherence)
    #pragma unroll
    for (int r = 0; r < 4; ++r) {
        int b = m0 + lq * 4 + r;
        if (!role) {
            int j = blk * 16 + lm;
            h1f[b * H_ + j] = h_reg[r]; c1f[b * H_ + j] = c_reg[r];
        } else if (lm < 8) {
            int j = (blk - 64) * 8 + lm;
            h2f[b * H_ + j] = h_reg[r]; c2f[b * H_ + j] = c_reg[r];
        }
    }
}

// ---------------- output fan-out ----------------
__global__ void write_out(const float* __restrict__ h1f, const float* __restrict__ h2f,
                          const float* __restrict__ c1f, const float* __restrict__ c2f,
                          float* __restrict__ out) {
    const long long EQ = (long long)B_ * H_ * 784;      // 51,380,224
    const long long n4 = (EQ + 4LL * B_ * H_) / 4;      // 12,910,592
    long long i4 = (long long)blockIdx.x * blockDim.x + threadIdx.x;
    long long stride = (long long)gridDim.x * blockDim.x;
    for (; i4 < n4; i4 += stride) {
        long long f = i4 * 4;
        float4 v;
        if (f < EQ) {
            long long bh = f / 784;
            float val = h2f[bh];
            v = make_float4(val, val, val, val);
        } else {
            long long r = f - EQ;
            int which = (int)(r >> 16);
            int j = (int)(r & 65535);
            const float* src = (which == 0) ? h1f : (which == 1) ? h2f : (which == 2) ? c1f : c2f;
            v = *reinterpret_cast<const float4*>(src + j);
        }
        reinterpret_cast<float4*>(out)[i4] = v;
    }
}

// ---------------- launch ----------------
extern "C" void kernel_launch(void* const* d_in, const int* in_sizes, int n_in,
                              void* d_out, int out_size, void* d_ws, size_t ws_size,
                              hipStream_t stream) {
    const int*   questions = (const int*)d_in[0];
    const int*   qlen      = (const int*)d_in[1];
    const float* embed     = (const float*)d_in[2];
    const float* W_ih1     = (const float*)d_in[3];
    const float* W_hh1     = (const float*)d_in[4];
    const float* b_ih1     = (const float*)d_in[5];
    const float* b_hh1     = (const float*)d_in[6];
    const float* W_ih2     = (const float*)d_in[7];
    const float* W_hh2     = (const float*)d_in[8];
    const float* b_ih2     = (const float*)d_in[9];
    const float* b_hh2     = (const float*)d_in[10];
    float* out = (float*)d_out;

    char* w = (char*)d_ws;
    float*    xg     = (float*)(w + 0);                 // 33,554,432
    ushort_t* Wih1p  = (ushort_t*)(w + 33554432);       //  2,621,440
    ushort_t* Xp     = (ushort_t*)(w + 36175872);       //  1,310,720
    ushort_t* h1hist = (ushort_t*)(w + 37486592);       // 33*131,072 = 4,325,376
    ushort_t* h2hist = (ushort_t*)(w + 41811968);       // 33*131,072 = 4,325,376
    float*    h1f    = (float*)(w + 46137344);          //    262,144
    float*    c1f    = (float*)(w + 46399488);
    float*    h2f    = (float*)(w + 46661632);
    float*    c2f    = (float*)(w + 46923776);
    int*      ctr    = (int*)(w + 47185920);            // 32*16*128 B = 65,536 (end 47,251,456)

    // zero initial-state slots (h1(-1), h2(-1)) and barrier counters
    hipMemsetAsync(w + 37486592, 0, 131072, stream);
    hipMemsetAsync(w + 41811968, 0, 131072, stream);
    hipMemsetAsync(w + 47185920, 0, 65536, stream);

    gather_embed<<<1280, 256, 0, stream>>>(questions, embed, Xp);
    pad_convert_wih1<<<2048, 256, 0, stream>>>(W_ih1, Wih1p);
    xgemm<<<dim3(32, 64), 256, 0, stream>>>(Xp, Wih1p, b_ih1, b_hh1, xg);

    lstm_persist<<<NBLK, 256, 0, stream>>>(W_hh1, W_ih2, W_hh2, b_ih2, b_hh2,
                                           xg, qlen,
                                           h1hist, h2hist,
                                           h1f, c1f, h2f, c2f, ctr);

    write_out<<<4096, 256, 0, stream>>>(h1f, h2f, c1f, c2f, out);
}

// Round 6
// 749.401 us; speedup vs baseline: 1.0379x; 1.0379x over previous
//
#include <hip/hip_runtime.h>
#include <hip/hip_bf16.h>
#include <cstdint>

#define B_  64
#define T_  32
#define E_  300
#define EP  320      // padded K for the x-precompute GEMM
#define H_  1024
#define G4  4096     // 4*H
#define BH  65536    // B_*H_
#define NBLK 192     // persistent blocks: 64 L1 + 128 L2

typedef __attribute__((ext_vector_type(8))) short bf16x8;
typedef __attribute__((ext_vector_type(4))) float f32x4;
typedef unsigned short ushort_t;

__device__ __forceinline__ bf16x8 load_b8(const ushort_t* p) {
    union { uint4 u; bf16x8 v; } c;
    c.u = *reinterpret_cast<const uint4*>(p);
    return c.v;
}

__device__ __forceinline__ ushort_t f2bf(float x) {
    union { float f; uint32_t u; } c; c.f = x;
    uint32_t r = c.u + 0x7fffu + ((c.u >> 16) & 1u);   // RNE
    return (ushort_t)(r >> 16);
}

__device__ __forceinline__ float sigm(float x) { return 1.0f / (1.0f + __expf(-x)); }

// agent-scope write-through store (producer side); consumers use plain cached
// loads — each timestep gets a unique buffer slot, so no stale lines exist.
__device__ __forceinline__ void astore16(ushort_t* p, ushort_t v) {
    __hip_atomic_store(p, v, __ATOMIC_RELAXED, __HIP_MEMORY_SCOPE_AGENT);
}
__device__ __forceinline__ int aload_i(const int* p) {
    return __hip_atomic_load(p, __ATOMIC_RELAXED, __HIP_MEMORY_SCOPE_AGENT);
}

// ---------------- prep kernels ----------------

__global__ void pad_convert_wih1(const float* __restrict__ src, ushort_t* __restrict__ dst) {
    int i = blockIdx.x * blockDim.x + threadIdx.x;
    int stride = gridDim.x * blockDim.x;
    const int n = G4 * EP;
    for (; i < n; i += stride) {
        int r = i / EP, c = i - r * EP;
        dst[i] = (c < E_) ? f2bf(src[r * E_ + c]) : (ushort_t)0;
    }
}

__global__ void gather_embed(const int* __restrict__ q, const float* __restrict__ table,
                             ushort_t* __restrict__ Xp) {
    int i = blockIdx.x * blockDim.x + threadIdx.x;
    int stride = gridDim.x * blockDim.x;
    const int n = B_ * T_ * EP;
    for (; i < n; i += stride) {
        int r = i / EP, c = i - r * EP;
        Xp[i] = (c < E_) ? f2bf(table[q[r] * E_ + c]) : (ushort_t)0;
    }
}

// ---------------- x-part precompute GEMM ----------------
// xg[t][b][4H] = Xp @ Wih1p^T + (b_ih1+b_hh1)
__launch_bounds__(256)
__global__ void xgemm(const ushort_t* __restrict__ Xp, const ushort_t* __restrict__ Wp,
                      const float* __restrict__ b_ih1, const float* __restrict__ b_hh1,
                      float* __restrict__ xg) {
    int mblk = blockIdx.x, nblk = blockIdx.y;
    int wave = threadIdx.x >> 6, lane = threadIdx.x & 63;
    int lm = lane & 15, lq = lane >> 4;
    int m0 = mblk * 64 + wave * 16;
    f32x4 acc[4];
    #pragma unroll
    for (int g = 0; g < 4; ++g) {
        int n = nblk * 64 + g * 16 + lm;
        float bv = b_ih1[n] + b_hh1[n];
        acc[g] = (f32x4){bv, bv, bv, bv};
    }
    for (int k0 = 0; k0 < EP; k0 += 32) {
        bf16x8 a = load_b8(Xp + (m0 + lm) * EP + k0 + lq * 8);
        #pragma unroll
        for (int g = 0; g < 4; ++g) {
            bf16x8 b = load_b8(Wp + (nblk * 64 + g * 16 + lm) * EP + k0 + lq * 8);
            acc[g] = __builtin_amdgcn_mfma_f32_16x16x32_bf16(a, b, acc[g], 0, 0, 0);
        }
    }
    #pragma unroll
    for (int g = 0; g < 4; ++g)
        #pragma unroll
        for (int r = 0; r < 4; ++r) {
            int m = m0 + lq * 4 + r;          // m = b*T + t
            int b = m >> 5, t = m & 31;
            int n = nblk * 64 + g * 16 + lm;
            xg[((size_t)t * B_ + b) * G4 + n] = acc[g][r];
        }
}

// ---------------- persistent recurrence kernel ----------------
// blocks 0-63:   L1, 16-col slices of layer1 (Whh1)
// blocks 64-191: L2, 8-col slices of layer2 (Wih2 + Whh2)
// K is split across the 4 waves (256 each); B-fragments live in VGPRs;
// partial sums reduced through LDS. Role-local step flags replace the
// global barrier: fl1[t] (64 arrivals), fl2[t] (128 arrivals).

__global__ __launch_bounds__(256, 1) void lstm_persist(
    const float* __restrict__ Whh1, const float* __restrict__ Wih2,
    const float* __restrict__ Whh2,
    const float* __restrict__ b_ih2, const float* __restrict__ b_hh2,
    const float* __restrict__ xg, const int* __restrict__ qlen,
    ushort_t* __restrict__ h1hist,   // 33 slots of BH bf16; slot k = h1(k-1)
    ushort_t* __restrict__ h2hist,   // 33 slots of BH bf16; slot k = h2(k-1)
    float* __restrict__ h1f, float* __restrict__ c1f,
    float* __restrict__ h2f, float* __restrict__ c2f,
    int* __restrict__ ctr)
{
    __shared__ ushort_t ws[65536];      // 128 KB: staging, then partial buffer

    const int blk  = blockIdx.x;
    const int role = (blk >= 64);       // 0=L1, 1=L2
    const int tid  = threadIdx.x;
    const int wave = tid >> 6, lane = tid & 63;
    const int lm = lane & 15, lq = lane >> 4;

    // ---- stage weights fp32 -> bf16 fragment layout in LDS (once) ----
    {
        const int k0c = tid >> 3;               // k/32
        const int klq = (tid >> 1) & 3;         // (k>>3)&3
        const int ke  = (tid & 1) * 4;          // k&7 (0 or 4)
        if (!role) {
            const int js = blk;                 // 16-col slice
            for (int r = 0; r < 64; ++r) {      // r = g*16 + lmt
                int g = r >> 4, lmt = r & 15;
                const float4 v = reinterpret_cast<const float4*>(
                    Whh1 + (size_t)(g * H_ + js * 16 + lmt) * H_)[tid];
                uint2 pk;
                pk.x = (uint32_t)f2bf(v.x) | ((uint32_t)f2bf(v.y) << 16);
                pk.y = (uint32_t)f2bf(v.z) | ((uint32_t)f2bf(v.w) << 16);
                int off = ((k0c * 4 + g) * 64 + klq * 16 + lmt) * 8 + ke;  // shorts
                *reinterpret_cast<uint2*>(ws + off) = pk;
            }
        } else {
            const int jj0 = (blk - 64) * 8;     // 8-col slice
            for (int m = 0; m < 2; ++m) {
                const float* Wm = m ? Whh2 : Wih2;
                for (int r = 0; r < 32; ++r) {  // r = g*8 + jj
                    int g = r >> 3, jj = r & 7;
                    int tl = r >> 4, lmt = r & 15;
                    const float4 v = reinterpret_cast<const float4*>(
                        Wm + (size_t)(g * H_ + jj0 + jj) * H_)[tid];
                    uint2 pk;
                    pk.x = (uint32_t)f2bf(v.x) | ((uint32_t)f2bf(v.y) << 16);
                    pk.y = (uint32_t)f2bf(v.z) | ((uint32_t)f2bf(v.w) << 16);
                    int off = m * 32768 + ((k0c * 2 + tl) * 64 + klq * 16 + lmt) * 8 + ke;
                    *reinterpret_cast<uint2*>(ws + off) = pk;
                }
            }
        }
    }
    __syncthreads();

    // ---- load this wave's K-quarter of B-fragments into registers ----
    bf16x8 Bf[32];
    if (!role) {
        #pragma unroll
        for (int kc = 0; kc < 8; ++kc)
            #pragma unroll
            for (int g = 0; g < 4; ++g)
                Bf[kc * 4 + g] = load_b8(ws + ((((wave * 8 + kc) * 4 + g)) << 9) + lane * 8);
    } else {
        #pragma unroll
        for (int mat = 0; mat < 2; ++mat)
            #pragma unroll
            for (int kc = 0; kc < 8; ++kc)
                #pragma unroll
                for (int tl = 0; tl < 2; ++tl)
                    Bf[mat * 16 + kc * 2 + tl] =
                        load_b8(ws + mat * 32768 + ((((wave * 8 + kc) * 2 + tl)) << 9) + lane * 8);
    }
    __syncthreads();                    // weights now in regs; ws reused below
    float* pbuf = reinterpret_cast<float*>(ws);

    int q[4];
    #pragma unroll
    for (int r = 0; r < 4; ++r) q[r] = qlen[wave * 16 + lq * 4 + r];

    float bi0 = 0.f, bi1 = 0.f;
    if (role) {
        const int jj0 = (blk - 64) * 8;
        int jj = lm & 7;
        int g0 = (lm < 8) ? 0 : 1, g1 = g0 + 2;
        bi0 = b_ih2[g0 * H_ + jj0 + jj] + b_hh2[g0 * H_ + jj0 + jj];
        bi1 = b_ih2[g1 * H_ + jj0 + jj] + b_hh2[g1 * H_ + jj0 + jj];
    }

    float    c_reg[4]  = {0.f, 0.f, 0.f, 0.f};
    float    h_reg[4]  = {0.f, 0.f, 0.f, 0.f};
    ushort_t hb_reg[4] = {0, 0, 0, 0};

    int* fl1 = ctr;                     // fl1[t] at ctr[t*32]
    int* fl2 = ctr + 64 * 32;           // fl2[t] at ctr[(64+t)*32]
    const int kbase = wave * 32 + lq;   // uint4 index base within a row (128/row)

    if (!role) {
        // =================== L1: h1(t) = cell(Whh1*h1(t-1) + xg[t]) ===================
        const int js = blk;
        for (int t = 0; t < T_; ++t) {
            // xg loads — independent of flags, issue early
            float xgv[4][4];
            #pragma unroll
            for (int g = 0; g < 4; ++g)
                #pragma unroll
                for (int r = 0; r < 4; ++r)
                    xgv[g][r] = xg[((size_t)t * B_ + (wave * 16 + lq * 4 + r)) * G4
                                   + g * H_ + js * 16 + lm];
            if (tid == 0 && t > 0)
                while (aload_i(&fl1[(t - 1) * 32]) < 64) __builtin_amdgcn_s_sleep(1);
            __syncthreads();

            const uint4* hq = reinterpret_cast<const uint4*>(h1hist + (size_t)t * BH);
            f32x4 acc[4][4];
            #pragma unroll
            for (int mt = 0; mt < 4; ++mt)
                #pragma unroll
                for (int g = 0; g < 4; ++g) acc[mt][g] = (f32x4){0.f, 0.f, 0.f, 0.f};

            uint4 abA[8], abB[8];
            #pragma unroll
            for (int kc = 0; kc < 8; ++kc) abA[kc] = hq[(size_t)lm * 128 + kbase + kc * 4];
            #pragma unroll
            for (int mt = 0; mt < 4; ++mt) {
                uint4* cur = (mt & 1) ? abB : abA;
                uint4* nxt = (mt & 1) ? abA : abB;
                if (mt < 3) {
                    #pragma unroll
                    for (int kc = 0; kc < 8; ++kc)
                        nxt[kc] = hq[(size_t)((mt + 1) * 16 + lm) * 128 + kbase + kc * 4];
                }
                #pragma unroll
                for (int kc = 0; kc < 8; ++kc) {
                    union { uint4 u; bf16x8 v; } a; a.u = cur[kc];
                    #pragma unroll
                    for (int g = 0; g < 4; ++g)
                        acc[mt][g] = __builtin_amdgcn_mfma_f32_16x16x32_bf16(
                            a.v, Bf[kc * 4 + g], acc[mt][g], 0, 0, 0);
                }
            }
            // partials -> LDS
            #pragma unroll
            for (int mt = 0; mt < 4; ++mt)
                #pragma unroll
                for (int g = 0; g < 4; ++g)
                    *reinterpret_cast<f32x4*>(pbuf + (wave * 16 + mt * 4 + g) * 256 + lane * 4)
                        = acc[mt][g];
            __syncthreads();
            // reduce own tile (mt = wave), add xg
            f32x4 red[4];
            #pragma unroll
            for (int g = 0; g < 4; ++g) {
                f32x4 s = *reinterpret_cast<const f32x4*>(
                    pbuf + (0 * 16 + wave * 4 + g) * 256 + lane * 4);
                #pragma unroll
                for (int src = 1; src < 4; ++src)
                    s += *reinterpret_cast<const f32x4*>(
                        pbuf + (src * 16 + wave * 4 + g) * 256 + lane * 4);
                #pragma unroll
                for (int r = 0; r < 4; ++r) s[r] += xgv[g][r];
                red[g] = s;
            }
            // epilogue
            ushort_t* hn = h1hist + (size_t)(t + 1) * BH;
            #pragma unroll
            for (int r = 0; r < 4; ++r) {
                int b = wave * 16 + lq * 4 + r, j = js * 16 + lm;
                if (t < q[r]) {
                    float iv = sigm(red[0][r]);
                    float fv = sigm(red[1][r]);
                    float gv = tanhf(red[2][r]);
                    float ov = sigm(red[3][r]);
                    float cn = fv * c_reg[r] + iv * gv;
                    float hv = ov * tanhf(cn);
                    c_reg[r] = cn; h_reg[r] = hv;
                    hb_reg[r] = f2bf(hv);
                }
                astore16(&hn[b * H_ + j], hb_reg[r]);
            }
            __syncthreads();            // drains vmcnt: h1(t) globally visible
            if (tid == 0)
                __hip_atomic_fetch_add(&fl1[t * 32], 1, __ATOMIC_RELAXED,
                                       __HIP_MEMORY_SCOPE_AGENT);
        }
        #pragma unroll
        for (int r = 0; r < 4; ++r) {
            int b = wave * 16 + lq * 4 + r, j = js * 16 + lm;
            h1f[b * H_ + j] = h_reg[r]; c1f[b * H_ + j] = c_reg[r];
        }
    } else {
        // ============ L2: h2(t) = cell(Wih2*h1(t) + Whh2*h2(t-1) + bias2) ============
        const int jj0 = (blk - 64) * 8;
        for (int t = 0; t < T_; ++t) {
            if (tid == 0) {
                while (aload_i(&fl1[t * 32]) < 64) __builtin_amdgcn_s_sleep(1);
                if (t > 0)
                    while (aload_i(&fl2[(t - 1) * 32]) < 128) __builtin_amdgcn_s_sleep(1);
            }
            __syncthreads();

            f32x4 acc[4][2];
            #pragma unroll
            for (int mt = 0; mt < 4; ++mt) {
                acc[mt][0] = (f32x4){0.f, 0.f, 0.f, 0.f};
                acc[mt][1] = (f32x4){0.f, 0.f, 0.f, 0.f};
            }
            #pragma unroll
            for (int mat = 0; mat < 2; ++mat) {
                const uint4* hq = reinterpret_cast<const uint4*>(
                    mat ? (h2hist + (size_t)t * BH) : (h1hist + (size_t)(t + 1) * BH));
                uint4 abA[8], abB[8];
                #pragma unroll
                for (int kc = 0; kc < 8; ++kc) abA[kc] = hq[(size_t)lm * 128 + kbase + kc * 4];
                #pragma unroll
                for (int mt = 0; mt < 4; ++mt) {
                    uint4* cur = (mt & 1) ? abB : abA;
                    uint4* nxt = (mt & 1) ? abA : abB;
                    if (mt < 3) {
                        #pragma unroll
                        for (int kc = 0; kc < 8; ++kc)
                            nxt[kc] = hq[(size_t)((mt + 1) * 16 + lm) * 128 + kbase + kc * 4];
                    }
                    #pragma unroll
                    for (int kc = 0; kc < 8; ++kc) {
                        union { uint4 u; bf16x8 v; } a; a.u = cur[kc];
                        #pragma unroll
                        for (int tl = 0; tl < 2; ++tl)
                            acc[mt][tl] = __builtin_amdgcn_mfma_f32_16x16x32_bf16(
                                a.v, Bf[mat * 16 + kc * 2 + tl], acc[mt][tl], 0, 0, 0);
                    }
                }
            }
            // partials -> LDS
            #pragma unroll
            for (int mt = 0; mt < 4; ++mt)
                #pragma unroll
                for (int tl = 0; tl < 2; ++tl)
                    *reinterpret_cast<f32x4*>(pbuf + (wave * 8 + mt * 2 + tl) * 256 + lane * 4)
                        = acc[mt][tl];
            __syncthreads();
            f32x4 red[2];
            #pragma unroll
            for (int tl = 0; tl < 2; ++tl) {
                f32x4 s = *reinterpret_cast<const f32x4*>(
                    pbuf + (0 * 8 + wave * 2 + tl) * 256 + lane * 4);
                #pragma unroll
                for (int src = 1; src < 4; ++src)
                    s += *reinterpret_cast<const f32x4*>(
                        pbuf + (src * 8 + wave * 2 + tl) * 256 + lane * 4);
                red[tl] = s;
            }
            #pragma unroll
            for (int r = 0; r < 4; ++r) { red[0][r] += bi0; red[1][r] += bi1; }
            // epilogue: tile0 = i|f, tile1 = g|o (split at lm==8)
            ushort_t* h2n = h2hist + (size_t)(t + 1) * BH;
            #pragma unroll
            for (int r = 0; r < 4; ++r) {
                float a0 = sigm(red[0][r]);                               // i or f
                float a1 = (lm < 8) ? tanhf(red[1][r]) : sigm(red[1][r]); // g or o
                float fo0 = __shfl_xor(a0, 8);                            // f for lm<8
                float fo1 = __shfl_xor(a1, 8);                            // o for lm<8
                if (lm < 8) {
                    int b = wave * 16 + lq * 4 + r, j = jj0 + lm;
                    if (t < q[r]) {
                        float cn = fo0 * c_reg[r] + a0 * a1;
                        float hv = fo1 * tanhf(cn);
                        c_reg[r] = cn; h_reg[r] = hv;
                        hb_reg[r] = f2bf(hv);
                    }
                    astore16(&h2n[b * H_ + j], hb_reg[r]);
                }
            }
            __syncthreads();            // drains vmcnt: h2(t) globally visible
            if (tid == 0)
                __hip_atomic_fetch_add(&fl2[t * 32], 1, __ATOMIC_RELAXED,
                                       __HIP_MEMORY_SCOPE_AGENT);
        }
        if (lm < 8) {
            #pragma unroll
            for (int r = 0; r < 4; ++r) {
                int b = wave * 16 + lq * 4 + r, j = jj0 + lm;
                h2f[b * H_ + j] = h_reg[r]; c2f[b * H_ + j] = c_reg[r];
            }
        }
    }
}

// ---------------- output fan-out ----------------
__global__ void write_out(const float* __restrict__ h1f, const float* __restrict__ h2f,
                          const float* __restrict__ c1f, const float* __restrict__ c2f,
                          float* __restrict__ out) {
    const long long EQ = (long long)B_ * H_ * 784;      // 51,380,224
    const long long n4 = (EQ + 4LL * B_ * H_) / 4;      // 12,910,592
    long long i4 = (long long)blockIdx.x * blockDim.x + threadIdx.x;
    long long stride = (long long)gridDim.x * blockDim.x;
    for (; i4 < n4; i4 += stride) {
        long long f = i4 * 4;
        float4 v;
        if (f < EQ) {
            long long bh = f / 784;
            float val = h2f[bh];
            v = make_float4(val, val, val, val);
        } else {
            long long r = f - EQ;
            int which = (int)(r >> 16);
            int j = (int)(r & 65535);
            const float* src = (which == 0) ? h1f : (which == 1) ? h2f : (which == 2) ? c1f : c2f;
            v = *reinterpret_cast<const float4*>(src + j);
        }
        reinterpret_cast<float4*>(out)[i4] = v;
    }
}

// ---------------- launch ----------------
extern "C" void kernel_launch(void* const* d_in, const int* in_sizes, int n_in,
                              void* d_out, int out_size, void* d_ws, size_t ws_size,
                              hipStream_t stream) {
    const int*   questions = (const int*)d_in[0];
    const int*   qlen      = (const int*)d_in[1];
    const float* embed     = (const float*)d_in[2];
    const float* W_ih1     = (const float*)d_in[3];
    const float* W_hh1     = (const float*)d_in[4];
    const float* b_ih1     = (const float*)d_in[5];
    const float* b_hh1     = (const float*)d_in[6];
    const float* W_ih2     = (const float*)d_in[7];
    const float* W_hh2     = (const float*)d_in[8];
    const float* b_ih2     = (const float*)d_in[9];
    const float* b_hh2     = (const float*)d_in[10];
    float* out = (float*)d_out;

    char* w = (char*)d_ws;
    float*    xg     = (float*)(w + 0);                 // 33,554,432
    ushort_t* Wih1p  = (ushort_t*)(w + 33554432);       //  2,621,440
    ushort_t* Xp     = (ushort_t*)(w + 36175872);       //  1,310,720
    ushort_t* h1hist = (ushort_t*)(w + 37486592);       // 33*131,072 = 4,325,376
    ushort_t* h2hist = (ushort_t*)(w + 41811968);       // 33*131,072 = 4,325,376
    float*    h1f    = (float*)(w + 46137344);          //    262,144
    float*    c1f    = (float*)(w + 46399488);
    float*    h2f    = (float*)(w + 46661632);
    float*    c2f    = (float*)(w + 46923776);
    int*      ctr    = (int*)(w + 47185920);            // 96*32 ints = 12,288 B

    // zero initial-state slots (h1(-1), h2(-1)) and step flags
    hipMemsetAsync(w + 37486592, 0, 131072, stream);
    hipMemsetAsync(w + 41811968, 0, 131072, stream);
    hipMemsetAsync(w + 47185920, 0, 96 * 32 * 4, stream);

    gather_embed<<<1280, 256, 0, stream>>>(questions, embed, Xp);
    pad_convert_wih1<<<2048, 256, 0, stream>>>(W_ih1, Wih1p);
    xgemm<<<dim3(32, 64), 256, 0, stream>>>(Xp, Wih1p, b_ih1, b_hh1, xg);

    lstm_persist<<<NBLK, 256, 0, stream>>>(W_hh1, W_ih2, W_hh2, b_ih2, b_hh2,
                                           xg, qlen,
                                           h1hist, h2hist,
                                           h1f, c1f, h2f, c2f, ctr);

    write_out<<<4096, 256, 0, stream>>>(h1f, h2f, c1f, c2f, out);
}